// Round 3
// baseline (9570.799 us; speedup 1.0000x reference)
//
#include <hip/hip_runtime.h>
#include <cstdint>

// Model dims (fixed)
#define Bb 8
#define Ll 512
#define Cc 512
#define Hh 8
#define HD 64
#define Ff 2048
#define Ss 50
#define NROWS 4096   // B*L

__device__ __forceinline__ float wave_sum(float v){
  #pragma unroll
  for (int o=32;o>=1;o>>=1) v += __shfl_xor(v,o);
  return v;
}
__device__ __forceinline__ float wave_max(float v){
  #pragma unroll
  for (int o=32;o>=1;o>>=1) v = fmaxf(v,__shfl_xor(v,o));
  return v;
}

// ---------------- embed gather: x[(b*L+l)*C+c] = embed[tok][c] ----------------
__global__ __launch_bounds__(128) void embed_k(const int* __restrict__ tok,
    const float* __restrict__ emb, float* __restrict__ x){
  int n = blockIdx.x;
  int t = tok[n];
  ((float4*)(x + ((size_t)n<<9)))[threadIdx.x] =
      ((const float4*)(emb + ((size_t)t<<9)))[threadIdx.x];
}

// ---------------- x *= mask[row] (in-place) ----------------
__global__ __launch_bounds__(256) void maskmul_k(float* __restrict__ x,
    const float* __restrict__ mask){
  int i = blockIdx.x*256 + threadIdx.x;        // float4 index
  float m = mask[i >> 7];                      // row = (4*i)/512
  float4 v = ((float4*)x)[i];
  v.x*=m; v.y*=m; v.z*=m; v.w*=m;
  ((float4*)x)[i]=v;
}

// ---------------- depthwise conv K=5, edge-replicate pad, +bias, *mask --------
__global__ __launch_bounds__(128) void dwconv_k(const float* __restrict__ x,
    const float* __restrict__ w, const float* __restrict__ bias,
    const float* __restrict__ mask, float* __restrict__ h){
  int n = blockIdx.x; int b_ = n >> 9, l = n & 511;
  int c0 = threadIdx.x * 4;
  float acc0=bias[c0], acc1=bias[c0+1], acc2=bias[c0+2], acc3=bias[c0+3];
  #pragma unroll
  for (int k=0;k<5;k++){
    int ls = l + k - 2; ls = ls < 0 ? 0 : (ls > 511 ? 511 : ls);
    const float4 xv = *(const float4*)&x[((size_t)(b_*512 + ls) << 9) + c0];
    acc0 += w[(c0+0)*5+k]*xv.x;
    acc1 += w[(c0+1)*5+k]*xv.y;
    acc2 += w[(c0+2)*5+k]*xv.z;
    acc3 += w[(c0+3)*5+k]*xv.w;
  }
  float mm = mask[n];
  float4 o; o.x=acc0*mm; o.y=acc1*mm; o.z=acc2*mm; o.w=acc3*mm;
  *(float4*)&h[((size_t)n << 9) + c0] = o;
}

// ---------------- rowwise LayerNorm over C=512: one wave per row ----------------
__global__ __launch_bounds__(256) void ln_rows(const float* __restrict__ x,
    const float* __restrict__ g, const float* __restrict__ bt,
    float* __restrict__ y, int nrows){
  int wid = threadIdx.x >> 6, lane = threadIdx.x & 63;
  int row = blockIdx.x*4 + wid;
  if (row >= nrows) return;
  const float4* xr = (const float4*)(x + ((size_t)row<<9));
  float4 a = xr[lane*2], b = xr[lane*2+1];
  float s = a.x+a.y+a.z+a.w+b.x+b.y+b.z+b.w;
  s = wave_sum(s);
  float m = s * (1.f/512.f);
  float d0=a.x-m,d1=a.y-m,d2=a.z-m,d3=a.w-m,d4=b.x-m,d5=b.y-m,d6=b.z-m,d7=b.w-m;
  float sq = d0*d0+d1*d1+d2*d2+d3*d3+d4*d4+d5*d5+d6*d6+d7*d7;
  sq = wave_sum(sq);
  float var = sq * (1.f/512.f);
  float inv = 1.f/sqrtf(var + 1e-6f);
  const float4* gr = (const float4*)g; const float4* br = (const float4*)bt;
  float4 g0=gr[lane*2], g1=gr[lane*2+1], b0=br[lane*2], b1=br[lane*2+1];
  float4 o0, o1;
  o0.x=d0*inv*g0.x+b0.x; o0.y=d1*inv*g0.y+b0.y; o0.z=d2*inv*g0.z+b0.z; o0.w=d3*inv*g0.w+b0.w;
  o1.x=d4*inv*g1.x+b1.x; o1.y=d5*inv*g1.y+b1.y; o1.z=d6*inv*g1.z+b1.z; o1.w=d7*inv*g1.w+b1.w;
  float4* yr = (float4*)(y + ((size_t)row<<9));
  yr[lane*2]=o0; yr[lane*2+1]=o1;
}

// ---------------- GEMM: Y[n,o] = sum_k A[n,k]*W[o,k]  (+ fused epilogues) -------
#define EPI_BIAS 0
#define EPI_SCALE 1
#define EPI_GELU 2
#define EPI_RES 3
#define EPI_RELU_MASK 4
#define EPI_RES_MASK 5
#define EPI_RES_GAMMA_MASK 6
#define EPI_TANH 7

template<int EPI, bool AMASK>
__global__ __launch_bounds__(256) void gemm_nt(
    const float* __restrict__ A, const float* __restrict__ W,
    const float* __restrict__ bias, const float* __restrict__ res,
    const float* __restrict__ gamma, const float* __restrict__ rowmask,
    float* __restrict__ Y, int N, int K, int O, float scale)
{
  __shared__ float As[16][68];
  __shared__ float Bs[16][68];
  int t = threadIdx.x;
  int tx = t & 15, ty = t >> 4;
  int row0 = blockIdx.y << 6, col0 = blockIdx.x << 6;
  int lr = t >> 2, lk = (t & 3) << 2;
  float acc[4][4] = {};
  int ar = row0 + lr;
  bool arok = ar < N;
  const float* Ap = A + (size_t)(arok ? ar : 0) * K + lk;
  const float* Wp = W + (size_t)(col0 + lr) * K + lk;
  float am = 1.f;
  if (AMASK) am = arok ? rowmask[ar] : 0.f;
  for (int k0 = 0; k0 < K; k0 += 16) {
    float4 av;
    if (arok) av = *(const float4*)(Ap + k0);
    else { av.x=0;av.y=0;av.z=0;av.w=0; }
    if (AMASK) { av.x*=am; av.y*=am; av.z*=am; av.w*=am; }
    float4 bv = *(const float4*)(Wp + k0);
    As[lk+0][lr]=av.x; As[lk+1][lr]=av.y; As[lk+2][lr]=av.z; As[lk+3][lr]=av.w;
    Bs[lk+0][lr]=bv.x; Bs[lk+1][lr]=bv.y; Bs[lk+2][lr]=bv.z; Bs[lk+3][lr]=bv.w;
    __syncthreads();
    #pragma unroll
    for (int k=0;k<16;k++){
      float4 af = *(const float4*)&As[k][ty<<2];
      float4 bf = *(const float4*)&Bs[k][tx<<2];
      float a4[4]={af.x,af.y,af.z,af.w};
      float b4[4]={bf.x,bf.y,bf.z,bf.w};
      #pragma unroll
      for (int i=0;i<4;i++)
        #pragma unroll
        for (int j=0;j<4;j++)
          acc[i][j] += a4[i]*b4[j];
    }
    __syncthreads();
  }
  #pragma unroll
  for (int i=0;i<4;i++){
    int row = row0 + (ty<<2) + i;
    if (row >= N) break;
    int colb = col0 + (tx<<2);
    float rm = 1.f;
    if (EPI==EPI_RELU_MASK || EPI==EPI_RES_MASK || EPI==EPI_RES_GAMMA_MASK)
      rm = rowmask[row];
    const float* rr = nullptr;
    if (EPI==EPI_RES || EPI==EPI_RES_MASK || EPI==EPI_RES_GAMMA_MASK)
      rr = res + (size_t)row*O + colb;
    float vv_[4];
    #pragma unroll
    for (int j=0;j<4;j++){
      float v = acc[i][j] + bias[colb+j];
      if constexpr (EPI==EPI_SCALE) v *= scale;
      else if constexpr (EPI==EPI_GELU) v = 0.5f*v*(1.f+erff(v*0.7071067811865475f));
      else if constexpr (EPI==EPI_RES) v = rr[j] + v;
      else if constexpr (EPI==EPI_RELU_MASK) v = fmaxf(v,0.f)*rm;
      else if constexpr (EPI==EPI_RES_MASK) v = rr[j] + v*rm;
      else if constexpr (EPI==EPI_RES_GAMMA_MASK) v = (rr[j] + gamma[colb+j]*v)*rm;
      else if constexpr (EPI==EPI_TANH) v = tanhf(v);
      vv_[j]=v;
    }
    float4 ov; ov.x=vv_[0]; ov.y=vv_[1]; ov.z=vv_[2]; ov.w=vv_[3];
    *(float4*)(Y + (size_t)row*O + colb) = ov;
  }
}

// ---------------- windowed-rel full attention: one block per (b,h,l) ----------
__global__ __launch_bounds__(256) void attn_k(const float* __restrict__ Q,
    const float* __restrict__ Kb, const float* __restrict__ Vb,
    const float* __restrict__ relk, const float* __restrict__ relv,
    const float* __restrict__ mask, float* __restrict__ O){
  int bid = blockIdx.x;
  int l = bid & 511; int bh = bid >> 9; int h = bh & 7; int b_ = bh >> 3;
  int t = threadIdx.x;
  __shared__ float qs[64];
  __shared__ float sc[512];
  __shared__ float red[4];
  __shared__ float part[4][64];
  size_t rowbase = ((size_t)(b_*512 + l) << 9) + h*64;
  if (t < 64) qs[t] = Q[rowbase + t];
  __syncthreads();
  float ml = mask[b_*512 + l];
  #pragma unroll
  for (int mi=0; mi<2; mi++){
    int m = t + mi*256;
    const float* kr = Kb + ((size_t)(b_*512+m)<<9) + h*64;
    float s = 0.f;
    #pragma unroll
    for (int d=0; d<64; d+=4){
      float4 kv = *(const float4*)&kr[d];
      s += qs[d]*kv.x + qs[d+1]*kv.y + qs[d+2]*kv.z + qs[d+3]*kv.w;
    }
    sc[m] = s;
  }
  __syncthreads();
  if (t < 64) {
    for (int j=0;j<9;j++){
      int m = l + j - 4;
      if (m >= 0 && m < 512) {
        float p = qs[t]*relk[j*64+t];
        p = wave_sum(p);
        if (t==0) sc[m] += p;
      }
    }
  }
  __syncthreads();
  { // attention mask (mask[b,l]*mask[b,m]==0 -> -10000), applied after rel add
    int m=t;     if (ml*mask[b_*512+m]==0.f) sc[m] = -10000.f;
    m = t+256;   if (ml*mask[b_*512+m]==0.f) sc[m] = -10000.f;
  }
  __syncthreads();
  float v0 = sc[t], v1 = sc[t+256];
  int wid = t>>6, lane = t&63;
  float lm = wave_max(fmaxf(v0,v1));
  if (lane==0) red[wid]=lm;
  __syncthreads();
  float mx = fmaxf(fmaxf(red[0],red[1]),fmaxf(red[2],red[3]));
  float e0 = expf(v0-mx), e1 = expf(v1-mx);
  float ls = wave_sum(e0+e1);
  __syncthreads();
  if (lane==0) red[wid]=ls;
  sc[t]=e0; sc[t+256]=e1;
  __syncthreads();
  float inv = 1.f/(red[0]+red[1]+red[2]+red[3]);
  // out = attn @ V
  int d = t & 63, grp = t >> 6;
  const float* vb = Vb + (((size_t)(b_*512))<<9) + h*64 + d;
  float acc = 0.f;
  for (int m = grp*128; m < grp*128+128; m++)
    acc += sc[m] * vb[((size_t)m)<<9];
  part[grp][d] = acc;
  __syncthreads();
  if (t < 64) {
    float o = part[0][t]+part[1][t]+part[2][t]+part[3][t];
    #pragma unroll
    for (int j=0;j<9;j++){
      int m = l + j - 4;
      if (m>=0 && m<512) o += sc[m]*relv[j*64+t];
    }
    O[rowbase + t] = o * inv;
  }
}

// ---------------- style attention: one block per (b,t) row, 2 waves = 2 heads --
__global__ __launch_bounds__(128) void style_attn_k(const float* __restrict__ Q,
    const float* __restrict__ kk, const float* __restrict__ vv,
    const float* __restrict__ mask, float* __restrict__ O){
  int n = blockIdx.x;
  int h = threadIdx.x >> 6, lane = threadIdx.x & 63;
  __shared__ float a[2][50];
  const float* q = Q + ((size_t)n<<9) + h*256;
  float4 qv = *(const float4*)&q[lane*4];
  for (int s=0;s<50;s++){
    const float* kr = kk + s*512 + h*256;
    float4 kv = *(const float4*)&kr[lane*4];
    float p = qv.x*kv.x+qv.y*kv.y+qv.z*kv.z+qv.w*kv.w;
    p = wave_sum(p);
    if (lane==0) a[h][s] = p * 0.044194173824159216f;   // C**-0.5
  }
  // per-head softmax over 50 (intra-wave)
  float e_ = (lane<50)? a[h][lane] : -1e30f;
  float mx = wave_max(e_);
  float ex = (lane<50)? expf(e_-mx) : 0.f;
  float sm = wave_sum(ex);
  float keep = (mask[n]==0.f) ? 0.f : 1.f;
  if (lane<50) a[h][lane] = ex/sm*keep;
  float4 o; o.x=0;o.y=0;o.z=0;o.w=0;
  for (int s=0;s<50;s++){
    float av = a[h][s];
    const float4 vvv = *(const float4*)&vv[s*512 + h*256 + lane*4];
    o.x += av*vvv.x; o.y += av*vvv.y; o.z += av*vvv.z; o.w += av*vvv.w;
  }
  *(float4*)&O[((size_t)n<<9) + h*256 + lane*4] = o;
}

// ---------------- final: out[b,c,l] = xn[b,l,c]*mask[b,l] ----------------
__global__ __launch_bounds__(256) void transpose_out_k(const float* __restrict__ xn,
    const float* __restrict__ mask, float* __restrict__ out){
  __shared__ float tile[32][33];
  int b_ = blockIdx.z; int c0 = blockIdx.x*32; int l0 = blockIdx.y*32;
  int tx = threadIdx.x & 31, ty = threadIdx.x >> 5;
  #pragma unroll
  for (int r=0;r<4;r++){
    int l = l0 + ty + r*8;
    tile[ty + r*8][tx] = xn[(((size_t)(b_*512 + l))<<9) + c0 + tx];
  }
  __syncthreads();
  float mm = mask[b_*512 + l0 + tx];
  #pragma unroll
  for (int r=0;r<4;r++){
    int c = c0 + ty + r*8;
    out[(((size_t)(b_*512 + c))<<9) + l0 + tx] = tile[tx][ty + r*8] * mm;
  }
}

extern "C" void kernel_launch(void* const* d_in, const int* in_sizes, int n_in,
                              void* d_out, int out_size, void* d_ws, size_t ws_size,
                              hipStream_t stream) {
  const int*   tokens   = (const int*)  d_in[0];
  const float* style_v  = (const float*)d_in[1];
  const float* mask     = (const float*)d_in[2];
  const float* embed_w  = (const float*)d_in[3];
  const float* cw_dw_w  = (const float*)d_in[4];
  const float* cw_dw_b  = (const float*)d_in[5];
  const float* cw_ln_g  = (const float*)d_in[6];
  const float* cw_ln_b  = (const float*)d_in[7];
  const float* cw_pw1_w = (const float*)d_in[8];
  const float* cw_pw1_b = (const float*)d_in[9];
  const float* cw_pw2_w = (const float*)d_in[10];
  const float* cw_pw2_b = (const float*)d_in[11];
  const float* cw_gamma = (const float*)d_in[12];
  const float* aq_w = (const float*)d_in[13];
  const float* aq_b = (const float*)d_in[14];
  const float* ak_w = (const float*)d_in[15];
  const float* ak_b = (const float*)d_in[16];
  const float* av_w = (const float*)d_in[17];
  const float* av_b = (const float*)d_in[18];
  const float* ao_w = (const float*)d_in[19];
  const float* ao_b = (const float*)d_in[20];
  const float* rel_k = (const float*)d_in[21];
  const float* rel_v = (const float*)d_in[22];
  const float* ln1_g = (const float*)d_in[23];
  const float* ln1_b = (const float*)d_in[24];
  const float* ln2_g = (const float*)d_in[25];
  const float* ln2_b = (const float*)d_in[26];
  const float* ffn_w1 = (const float*)d_in[27];
  const float* ffn_b1 = (const float*)d_in[28];
  const float* ffn_w2 = (const float*)d_in[29];
  const float* ffn_b2 = (const float*)d_in[30];
  const float* style_key = (const float*)d_in[31];
  const float* sq_w = (const float*)d_in[32];
  const float* sq_b = (const float*)d_in[33];
  const float* sk_w = (const float*)d_in[34];
  const float* sk_b = (const float*)d_in[35];
  const float* sv_w = (const float*)d_in[36];
  const float* sv_b = (const float*)d_in[37];
  const float* so_w = (const float*)d_in[38];
  const float* so_b = (const float*)d_in[39];
  const float* sn_g = (const float*)d_in[40];
  const float* sn_b = (const float*)d_in[41];

  const int N = NROWS;           // 4096 rows
  float* ws = (float*)d_ws;
  float* X  = ws;                         // (N,512)
  float* T  = X  + (size_t)N*512;         // (N,512)
  float* Qb = T  + (size_t)N*512;         // (N,512)
  float* Kb = Qb + (size_t)N*512;         // (N,512)
  float* Vb = Kb + (size_t)N*512;         // (N,512)
  float* Hb = Vb + (size_t)N*512;         // (N,2048)
  float* KK = Hb + (size_t)N*2048;        // 2*(50,512)
  float* VV = KK + 2*50*512;              // 2*(50,512)

  dim3 g512(8, 64), g2048(32, 64), gS(8, 1);

  embed_k<<<4096,128,0,stream>>>(tokens, embed_w, X);

  // ---- ConvNeXt blocks ----
  for (int i=0;i<4;i++){
    maskmul_k<<<2048,256,0,stream>>>(X, mask);
    dwconv_k<<<4096,128,0,stream>>>(X, cw_dw_w + (size_t)i*512*5, cw_dw_b + i*512, mask, T);
    ln_rows<<<1024,256,0,stream>>>(T, cw_ln_g+i*512, cw_ln_b+i*512, T, N);
    gemm_nt<EPI_GELU,false><<<g2048,256,0,stream>>>(T, cw_pw1_w + (size_t)i*2048*512,
        cw_pw1_b+i*2048, nullptr, nullptr, nullptr, Hb, N, 512, 2048, 0.f);
    gemm_nt<EPI_RES_GAMMA_MASK,false><<<g512,256,0,stream>>>(Hb, cw_pw2_w + (size_t)i*512*2048,
        cw_pw2_b+i*512, X, cw_gamma+i*512, mask, X, N, 2048, 512, 0.f);
  }
  maskmul_k<<<2048,256,0,stream>>>(X, mask);

  // ---- Attention layers ----
  for (int i=0;i<6;i++){
    size_t wo = (size_t)i*512*512;
    gemm_nt<EPI_SCALE,false><<<g512,256,0,stream>>>(X, aq_w+wo, aq_b+i*512,
        nullptr,nullptr,nullptr, Qb, N,512,512, 0.125f);
    gemm_nt<EPI_BIAS,false><<<g512,256,0,stream>>>(X, ak_w+wo, ak_b+i*512,
        nullptr,nullptr,nullptr, Kb, N,512,512, 0.f);
    gemm_nt<EPI_BIAS,false><<<g512,256,0,stream>>>(X, av_w+wo, av_b+i*512,
        nullptr,nullptr,nullptr, Vb, N,512,512, 0.f);
    attn_k<<<32768,256,0,stream>>>(Qb, Kb, Vb, rel_k + (size_t)i*9*64,
        rel_v + (size_t)i*9*64, mask, T);
    gemm_nt<EPI_RES,false><<<g512,256,0,stream>>>(T, ao_w+wo, ao_b+i*512,
        X, nullptr, nullptr, Qb, N,512,512, 0.f);
    ln_rows<<<1024,256,0,stream>>>(Qb, ln1_g+i*512, ln1_b+i*512, X, N);
    gemm_nt<EPI_RELU_MASK,true><<<g2048,256,0,stream>>>(X, ffn_w1 + (size_t)i*2048*512,
        ffn_b1+i*2048, nullptr, nullptr, mask, Hb, N,512,2048, 0.f);
    gemm_nt<EPI_RES_MASK,false><<<g512,256,0,stream>>>(Hb, ffn_w2 + (size_t)i*512*2048,
        ffn_b2+i*512, X, nullptr, mask, Qb, N,2048,512, 0.f);
    ln_rows<<<1024,256,0,stream>>>(Qb, ln2_g+i*512, ln2_b+i*512, X, N);
  }
  maskmul_k<<<2048,256,0,stream>>>(X, mask);

  // ---- Style attention ----
  gemm_nt<EPI_TANH,false><<<gS,256,0,stream>>>(style_key, sk_w, sk_b,
      nullptr,nullptr,nullptr, KK, 50,512,512, 0.f);
  gemm_nt<EPI_TANH,false><<<gS,256,0,stream>>>(style_key, sk_w+262144, sk_b+512,
      nullptr,nullptr,nullptr, KK+25600, 50,512,512, 0.f);
  gemm_nt<EPI_BIAS,false><<<gS,256,0,stream>>>(style_v, sv_w, sv_b,
      nullptr,nullptr,nullptr, VV, 50,512,512, 0.f);
  gemm_nt<EPI_BIAS,false><<<gS,256,0,stream>>>(style_v, sv_w+262144, sv_b+512,
      nullptr,nullptr,nullptr, VV+25600, 50,512,512, 0.f);

  // layer 0: xin = X (xt)
  gemm_nt<EPI_BIAS,false><<<g512,256,0,stream>>>(X, sq_w, sq_b,
      nullptr,nullptr,nullptr, Qb, N,512,512, 0.f);
  style_attn_k<<<4096,128,0,stream>>>(Qb, KK, VV, mask, T);
  gemm_nt<EPI_RES_MASK,false><<<g512,256,0,stream>>>(T, so_w, so_b,
      X, nullptr, mask, Kb, N,512,512, 0.f);          // x1 = xt + o*mask
  // layer 1: xin = x1 (Kb); residual still xt (X)
  gemm_nt<EPI_BIAS,false><<<g512,256,0,stream>>>(Kb, sq_w+262144, sq_b+512,
      nullptr,nullptr,nullptr, Qb, N,512,512, 0.f);
  style_attn_k<<<4096,128,0,stream>>>(Qb, KK+25600, VV+25600, mask, T);
  gemm_nt<EPI_RES_MASK,false><<<g512,256,0,stream>>>(T, so_w+262144, so_b+512,
      X, nullptr, mask, Vb, N,512,512, 0.f);          // x2 = xt + o*mask

  ln_rows<<<1024,256,0,stream>>>(Vb, sn_g, sn_b, Qb, N);
  transpose_out_k<<<dim3(16,16,8),256,0,stream>>>(Qb, mask, (float*)d_out);
}